// Round 9
// baseline (136.896 us; speedup 1.0000x reference)
//
#include <hip/hip_runtime.h>
#include <stdint.h>

// CRF loss: S=32768, L=512 — R9: R8 ping-pong + OOB-read fix.
// R8 NaN root cause: feature read addr fa1 computed as fa0+64, but the
// staging swizzle is an XOR (scl=(cl&7)<<4, bits 4-6) — (ib+64)^scl != 
// (ib^scl)+64 when scl bit 6 is set. For cl=15 the bogus address ran past
// the LDS allocation -> garbage floats -> exp -> inf -> renorm sc=0 -> P=0
// -> log(0) -> NaN. Fix: fa1 = cl*2048 + ((ib+64)^scl), matching the
// involution (LDS byte = global byte ^ scl within each 2KB row).
// Structure (unchanged from R8): each block owns 32 chunks as two 16-col
// tiles (NCF=4096, CH=8); every half-step runs MFMA(X) CONCURRENTLY with
// renorm-finish(Y) (disjoint regs/LDS, different pipes) to hide the serial
// renorm chain that left the matrix pipe idle in R7's lockstep (48us vs
// 16.6us MFMA floor). Pl single-buffered per tile (WAR split by half-step
// barrier); feature ring 2-deep per tile (4x32KB); vmcnt(2) half-step
// barriers (staging lead ~2600cy >> 900cy HBM), vmcnt(0) only at the tail
// where staging skips break the count.
//   crf_prep:   fp8 A-frags of E'=2*exp(T), E'^T; gold partials. 256x1024.
//   crf_chunks: ping-pong fwd/bwd, 2x16 MFMA cols/block. 256x1024.
//   crf_lse:    per-chunk stitch lse terms, one wave per chunk. 512x512.
//   crf_final:  reduction -> out[0]. 1x512.

#define S_LEN 32768
#define L 512
#define CH 8
#define NCF 4096            // chunks (c = 0..4095)
#define NB  256
#define TPB 1024
#define LN448 6.104793232f
#define LN2   0.6931471806f

// ws layout (bytes)
#define OFF_EAF  0                       // 256 KB: A-frag fp8 of E'   (fwd)
#define OFF_EAB  (256*1024)              // 256 KB: A-frag fp8 of E'^T (bwd)
#define OFF_G    (512*1024)              // 4096*512 bf16 (4 MB)
#define OFF_H    (OFF_G + NCF*512*2)     // 4096*512 bf16 (4 MB, row 0 unused)
#define OFF_LSE  (OFF_H + NCF*512*2)     // 2*4096+1 f32
#define OFF_GOLD (OFF_LSE + (2*NCF+8)*4) // 256 f32 gold partials

// dynamic LDS layout for crf_chunks (bytes)
#define PL_A   0                         // 8 KB fp8 P, tile A
#define PL_B   8192                      // 8 KB fp8 P, tile B
#define SPA    16384                     // sPart tile A [16][20] f32
#define SPB    17664                     // sPart tile B [16][20] f32
#define LF     19456                     // ring: [par][tile][16 waves][2048]
#define SMEM_TOTAL (19456 + 4*32768)     // 150528

typedef float v4f __attribute__((ext_vector_type(4)));

__device__ __forceinline__ float b2f(unsigned short u){
  return __uint_as_float(((unsigned)u) << 16);
}
__device__ __forceinline__ unsigned short f2b(float x){
  unsigned u = __float_as_uint(x);
  return (unsigned short)((u + 0x7fffu + ((u >> 16) & 1u)) >> 16);
}
__device__ __forceinline__ unsigned char to_fp8(float v){
  int u = __builtin_amdgcn_cvt_pk_fp8_f32(v, v, 0, false);
  return (unsigned char)(u & 0xff);
}

// async global->LDS, 16B per lane; dst = wave-uniform base (HW adds lane*16),
// src is per-lane.
__device__ __forceinline__ void gl2lds16(const void* g, void* l){
  __builtin_amdgcn_global_load_lds(
      (const __attribute__((address_space(1))) void*)g,
      (__attribute__((address_space(3))) void*)l, 16, 0, 0);
}

// workgroup barrier, LDS-visibility only (no vmcnt drain).
__device__ __forceinline__ void lds_sync(){
  asm volatile("s_waitcnt lgkmcnt(0)" ::: "memory");
  __builtin_amdgcn_sched_barrier(0);
  __builtin_amdgcn_s_barrier();
  __builtin_amdgcn_sched_barrier(0);
}
// half-step barrier: LDS visible + newest 2 staging loads may stay in flight.
__device__ __forceinline__ void sync2(){
  asm volatile("s_waitcnt vmcnt(2) lgkmcnt(0)" ::: "memory");
  __builtin_amdgcn_sched_barrier(0);
  __builtin_amdgcn_s_barrier();
  __builtin_amdgcn_sched_barrier(0);
}
// draining variant for tail half-steps where a staging skip breaks the count.
__device__ __forceinline__ void sync0(){
  asm volatile("s_waitcnt vmcnt(0) lgkmcnt(0)" ::: "memory");
  __builtin_amdgcn_sched_barrier(0);
  __builtin_amdgcn_s_barrier();
  __builtin_amdgcn_sched_barrier(0);
}

__device__ __forceinline__ float waveMax(float v){
  #pragma unroll
  for (int off = 32; off >= 1; off >>= 1) v = fmaxf(v, __shfl_xor(v, off));
  return v;
}
__device__ __forceinline__ float waveSum(float v){
  #pragma unroll
  for (int off = 32; off >= 1; off >>= 1) v += __shfl_xor(v, off);
  return v;
}

// block sum for 16-wave (1024-thr) blocks; sred: float[17]
__device__ __forceinline__ float blockSum16(float v, float* sred){
  #pragma unroll
  for (int off = 32; off >= 1; off >>= 1) v += __shfl_xor(v, off);
  int wid = threadIdx.x >> 6, lane = threadIdx.x & 63;
  if (lane == 0) sred[wid] = v;
  __syncthreads();
  if (threadIdx.x < 16) {
    float t = sred[threadIdx.x];
    t += __shfl_xor(t, 8); t += __shfl_xor(t, 4);
    t += __shfl_xor(t, 2); t += __shfl_xor(t, 1);
    if (threadIdx.x == 0) sred[16] = t;
  }
  __syncthreads();
  float r = sred[16];
  __syncthreads();
  return r;
}
// block sum for 8-wave (512-thr) blocks; sred: float[9]
__device__ __forceinline__ float blockSum8(float v, float* sred){
  #pragma unroll
  for (int off = 32; off >= 1; off >>= 1) v += __shfl_xor(v, off);
  int wid = threadIdx.x >> 6, lane = threadIdx.x & 63;
  if (lane == 0) sred[wid] = v;
  __syncthreads();
  if (threadIdx.x < 8) {
    float t = sred[threadIdx.x];
    t += __shfl_xor(t, 4); t += __shfl_xor(t, 2); t += __shfl_xor(t, 1);
    if (threadIdx.x == 0) sred[8] = t;
  }
  __syncthreads();
  float r = sred[8];
  __syncthreads();
  return r;
}

// ---------------- prep: E' fragments + gold partials ----------------
// A-frag layout: byte (R16*16+kt)*512 + lane*8 + r holds
//   Mat[m = R16*16+(lane&15)][k = kt*32+(lane>>4)*8+r]
extern "C" __global__ __launch_bounds__(TPB)
void crf_prep(const float* __restrict__ logit,
              const int* __restrict__ labels,
              const float* __restrict__ T,
              unsigned char* __restrict__ EAf,
              unsigned char* __restrict__ EAb,
              float* __restrict__ part){
  __shared__ float sredG[17];
  const int tidx = threadIdx.x;
  {
    int tid = blockIdx.x*TPB + tidx;     // 0..262143, exactly one pass
    int r    = tid & 7;
    int lane = (tid >> 3) & 63;
    int kt   = (tid >> 9) & 15;
    int R16  = tid >> 13;                // 0..31
    int j = R16*16 + (lane & 15);
    int i = kt*32 + ((lane >> 4) << 3) + r;
    EAf[tid] = to_fp8(2.0f * __expf(T[j*L + i]));  // E'[j][i]
    EAb[tid] = to_fp8(2.0f * __expf(T[i*L + j]));  // E'^T[j][i]
  }
  {
    float acc = 0.f;
    if (tidx < 128) {
      int t = blockIdx.x*128 + tidx;     // covers 0..32767 exactly
      int yt = labels[t];
      float v = logit[(size_t)t*L + yt];
      if (t > 0) v += T[yt*L + labels[t-1]];
      acc = v;
    }
    float s = blockSum16(acc, sredG);
    if (tidx == 0) part[blockIdx.x] = s;
  }
}

// ---------------- chunks: ping-pong forward/backward recurrence ----------
extern "C" __global__ __launch_bounds__(TPB, 4)
void crf_chunks(const float* __restrict__ logit,
                const unsigned char* __restrict__ EAf,
                const unsigned char* __restrict__ EAb,
                unsigned short* __restrict__ G,
                unsigned short* __restrict__ H){
  extern __shared__ __align__(16) char smem[];

  const int tidx = threadIdx.x;
  const int w    = tidx >> 6;                    // wave 0..15, owns 32 rows
  const int lane = tidx & 63;
  const int quad = lane >> 4;
  const int cl   = lane & 15;                    // MFMA column within tile
  const bool fwd = (blockIdx.x < NB/2);
  const int  b   = fwd ? blockIdx.x : (blockIdx.x - NB/2);
  const int  base = (fwd ? 0 : 1) + b*32;
  const int  cgA  = base + cl;                   // tile A chunk
  const int  cgB  = cgA + 16;                    // tile B chunk
  const int  cgcA = min(cgA, NCF-1);
  const int  cgcB = min(cgB, NCF-1);
  const bool isc0 = fwd && (cgA == 0);
  const int  jrow0 = w*32 + quad*4;

  // staging: wave w stages column w of each tile
  const int  cgsA = min(base + w,      NCF-1);
  const int  cgsB = min(base + 16 + w, NCF-1);
  const unsigned so = ((unsigned)(lane*16)) ^ ((unsigned)((w & 7) << 4));

  // E' A-fragments: 32 longs = 64 acc-regs per wave (shared by both tiles)
  const long* EAp = (const long*)(fwd ? EAf : EAb);
  long eA[2][16];
  #pragma unroll
  for (int mt = 0; mt < 2; ++mt)
    #pragma unroll
    for (int kt = 0; kt < 16; ++kt)
      eA[mt][kt] = EAp[(((w*2 + mt)*16) + kt)*64 + lane];

  // LDS addresses (constant per thread); second row-block = +256 immediate,
  // tile B = +8192 immediate.
  const int pladdr = (jrow0 >> 5)*512 + ((((jrow0 >> 3) & 3)*16 + cl) << 3)
                   + (jrow0 & 7);
  const int bbb = lane*8;                        // MFMA B-read base (+kt*512)
  // feature read addrs: LDS byte = global byte ^ scl within the 2KB row
  // (staged by wave cl with swizzle scl). fa1 MUST apply XOR after +64 —
  // fa0+64 was R8's OOB/NaN bug.
  const int scl = (cl & 7) << 4;
  const int ib  = w*128 + quad*16;
  const int fa0 = LF + cl*2048 + (ib ^ scl);
  const int fa1 = LF + cl*2048 + ((ib + 64) ^ scl);

  auto stage = [&](int tile, int ks){
    int cgs = tile ? cgsB : cgsA;
    int t = fwd ? (cgs*CH + ks) : (cgs*CH + CH - 2 - ks);
    const char* row = (const char*)logit + (size_t)t*(L*4);
    char* dst = smem + (LF + ((ks & 1) << 16) + (tile << 15) + w*2048);
    gl2lds16(row + so, dst);
    gl2lds16(row + 1024 + so, dst + 1024);
  };
  auto wmax = [&](v4f x0, v4f x1, int spoff){
    float mx = fmaxf(fmaxf(fmaxf(x0[0],x0[1]),fmaxf(x0[2],x0[3])),
                     fmaxf(fmaxf(x1[0],x1[1]),fmaxf(x1[2],x1[3])));
    mx = fmaxf(mx, __shfl_xor(mx, 16));
    mx = fmaxf(mx, __shfl_xor(mx, 32));          // column max within wave
    if (quad == 0) *(float*)(smem + spoff + cl*80 + w*4) = mx;
  };
  auto s2 = [&](v4f x0, v4f x1, int spoff, int ploff, float& m){
    const char* spb = smem + spoff + cl*80;
    float4 q0 = *(const float4*)spb;
    float4 q1 = *(const float4*)(spb + 16);
    float4 q2 = *(const float4*)(spb + 32);
    float4 q3 = *(const float4*)(spb + 48);
    float M = fmaxf(fmaxf(fmaxf(fmaxf(q0.x,q0.y),fmaxf(q0.z,q0.w)),
                          fmaxf(fmaxf(q1.x,q1.y),fmaxf(q1.z,q1.w))),
                    fmaxf(fmaxf(fmaxf(q2.x,q2.y),fmaxf(q2.z,q2.w)),
                          fmaxf(fmaxf(q3.x,q3.y),fmaxf(q3.z,q3.w))));
    float sc = 448.0f / M;
    int u0 = __builtin_amdgcn_cvt_pk_fp8_f32(x0[0]*sc, x0[1]*sc, 0, false);
    u0     = __builtin_amdgcn_cvt_pk_fp8_f32(x0[2]*sc, x0[3]*sc, u0, true);
    *(int*)(smem + ploff + pladdr) = u0;
    int u1 = __builtin_amdgcn_cvt_pk_fp8_f32(x1[0]*sc, x1[1]*sc, 0, false);
    u1     = __builtin_amdgcn_cvt_pk_fp8_f32(x1[2]*sc, x1[3]*sc, u1, true);
    *(int*)(smem + ploff + pladdr + 256) = u1;
    m += __logf(M) - LN448;
  };
  auto fmul = [&](v4f& x0, v4f& x1, int fbase, bool anchor){
    const char* fb = smem + fbase;
    float4 q0 = *(const float4*)(fb + fa0);
    float4 q1 = *(const float4*)(fb + fa1);
    float f0=__expf(q0.x), f1=__expf(q0.y), f2=__expf(q0.z), f3=__expf(q0.w);
    float g0=__expf(q1.x), g1=__expf(q1.y), g2=__expf(q1.z), g3=__expf(q1.w);
    if (anchor) {                   // chunk 0 exact anchor: alpha_0 = exp(f0)
      x0 = (v4f){f0,f1,f2,f3};  x1 = (v4f){g0,g1,g2,g3};
    } else {
      x0 = (v4f){x0[0]*f0, x0[1]*f1, x0[2]*f2, x0[3]*f3};
      x1 = (v4f){x1[0]*g0, x1[1]*g1, x1[2]*g2, x1[3]*g3};
    }
  };
  auto store_out = [&](v4f x0, v4f x1, float m, int cg, bool anchor){
    if (cg <= NCF-1) {
      // folded E'=2E compensation: CH steps (CH-1 for the anchored column)
      float madj = m - (anchor ? (float)(CH-1) : (float)CH)*LN2;
      unsigned short* dst = (fwd ? G : H) + (size_t)cg*L + jrow0;
      unsigned long long pv =
           (unsigned long long)f2b(__logf(x0[0]) + madj)
        | ((unsigned long long)f2b(__logf(x0[1]) + madj) << 16)
        | ((unsigned long long)f2b(__logf(x0[2]) + madj) << 32)
        | ((unsigned long long)f2b(__logf(x0[3]) + madj) << 48);
      *(unsigned long long*)dst = pv;
      pv = (unsigned long long)f2b(__logf(x1[0]) + madj)
        | ((unsigned long long)f2b(__logf(x1[1]) + madj) << 16)
        | ((unsigned long long)f2b(__logf(x1[2]) + madj) << 32)
        | ((unsigned long long)f2b(__logf(x1[3]) + madj) << 48);
      *(unsigned long long*)(dst + 16) = pv;
    }
  };

  // ---- prologue: start DMA for step 0 of both tiles, init, double renorm --
  stage(0, 0);  stage(1, 0);

  v4f vA0, vA1, vB0, vB1;
  if (fwd) {
    vA0 = (v4f){1.f,1.f,1.f,1.f}; vA1 = vA0; vB0 = vA0; vB1 = vA0;
  } else {
    const float* ip = logit + (size_t)(cgcA*CH + CH - 1)*L + jrow0;
    float4 x0 = *(const float4*)ip, x1 = *(const float4*)(ip + 16);
    vA0 = (v4f){__expf(x0.x),__expf(x0.y),__expf(x0.z),__expf(x0.w)};
    vA1 = (v4f){__expf(x1.x),__expf(x1.y),__expf(x1.z),__expf(x1.w)};
    ip = logit + (size_t)(cgcB*CH + CH - 1)*L + jrow0;
    x0 = *(const float4*)ip; x1 = *(const float4*)(ip + 16);
    vB0 = (v4f){__expf(x0.x),__expf(x0.y),__expf(x0.z),__expf(x0.w)};
    vB1 = (v4f){__expf(x1.x),__expf(x1.y),__expf(x1.z),__expf(x1.w)};
  }
  float mA = 0.0f, mB = 0.0f;

  wmax(vA0, vA1, SPA);
  wmax(vB0, vB1, SPB);
  lds_sync();
  s2(vA0, vA1, SPA, PL_A, mA);       // Pl_A ready for halfA(0)
  sync2();                           // everything except newest 2 staged

  // ---- main loop: 8 steps x {halfA, halfB} -------------------------------
  #pragma unroll
  for (int k = 0; k < CH; ++k) {
    const bool last = (k == CH-1);
    // ---------- half A: MFMA(A,k) || S2(B,k-1/init) ----------
    {
      if (fwd ? (k+1 <= CH-1) : (k+1 <= CH-2)) stage(0, k+1);
      v4f a0 = (v4f){0.f,0.f,0.f,0.f};
      v4f a1 = (v4f){0.f,0.f,0.f,0.f};
      #pragma unroll
      for (int kt = 0; kt < 16; ++kt) {
        long bbv = *(const long*)(smem + PL_A + bbb + kt*512);
        a0 = __builtin_amdgcn_mfma_f32_16x16x32_fp8_fp8(eA[0][kt], bbv, a0, 0, 0, 0);
        a1 = __builtin_amdgcn_mfma_f32_16x16x32_fp8_fp8(eA[1][kt], bbv, a1, 0, 0, 0);
      }
      s2(vB0, vB1, SPB, PL_B, mB);   // k=0: S2(B,init); writes Pl_B for halfB
      if (fwd || !last) fmul(a0, a1, ((k & 1) << 16), k == 0 && isc0);
      if (k == 0 && isc0) mA = 0.0f;
      if (last) {
        store_out(a0, a1, mA, cgA, isc0);
      } else {
        vA0 = a0; vA1 = a1;
        wmax(vA0, vA1, SPA);
      }
      if (k >= CH-2) sync0(); else sync2();
    }
    // ---------- half B: MFMA(B,k) || S2(A,k) ----------
    {
      if (fwd ? (k+1 <= CH-1) : (k+1 <= CH-2)) stage(1, k+1);
      v4f b0 = (v4f){0.f,0.f,0.f,0.f};
      v4f b1 = (v4f){0.f,0.f,0.f,0.f};
      #pragma unroll
      for (int kt = 0; kt < 16; ++kt) {
        long bbv = *(const long*)(smem + PL_B + bbb + kt*512);
        b0 = __builtin_amdgcn_mfma_f32_16x16x32_fp8_fp8(eA[0][kt], bbv, b0, 0, 0, 0);
        b1 = __builtin_amdgcn_mfma_f32_16x16x32_fp8_fp8(eA[1][kt], bbv, b1, 0, 0, 0);
      }
      if (!last) s2(vA0, vA1, SPA, PL_A, mA);   // writes Pl_A for step k+1
      if (fwd || !last) fmul(b0, b1, ((k & 1) << 16) + 32768, false);
      if (last) {
        store_out(b0, b1, mB, cgB, false);
      } else {
        vB0 = b0; vB1 = b1;
        wmax(vB0, vB1, SPB);
        sync2();
      }
    }
  }
}

// ---------------- lse: stitch terms — one WAVE per chunk ----------------
extern "C" __global__ __launch_bounds__(512)
void crf_lse(const unsigned short* __restrict__ G,
             const unsigned short* __restrict__ H,
             float* __restrict__ lsebuf){
  const int tidx = threadIdx.x;
  const int w    = tidx >> 6;
  const int lane = tidx & 63;
  const int g    = blockIdx.x*8 + w;             // 0..4095
  const int j8   = lane*8;
  if (g == 0) {
    const unsigned short* p = G + (size_t)(NCF-1)*L + j8;
    ushort4 a = *(const ushort4*)p, bq = *(const ushort4*)(p + 4);
    float v[8] = { b2f(a.x),b2f(a.y),b2f(a.z),b2f(a.w),
                   b2f(bq.x),b2f(bq.y),b2f(bq.z),b2f(bq.w) };
    float mx = v[0];
    #pragma unroll
    for (int r = 1; r < 8; ++r) mx = fmaxf(mx, v[r]);
    mx = waveMax(mx);
    float s = 0.f;
    #pragma unroll
    for (int r = 0; r < 8; ++r) s += __expf(v[r] - mx);
    s = waveSum(s);
    if (lane == 0) lsebuf[2*NCF] = mx + __logf(s);
  } else {
    const unsigned short* hp = H + (size_t)g*L + j8;
    const unsigned short* gp = G + (size_t)(g-1)*L + j8;
    ushort4 ha = *(const ushort4*)hp, hb = *(const ushort4*)(hp + 4);
    ushort4 ga = *(const ushort4*)gp, gb = *(const ushort4*)(gp + 4);
    float hv[8] = { b2f(ha.x),b2f(ha.y),b2f(ha.z),b2f(ha.w),
                    b2f(hb.x),b2f(hb.y),b2f(hb.z),b2f(hb.w) };
    float gv[8] = { b2f(ga.x),b2f(ga.y),b2f(ga.z),b2f(ga.w),
                    b2f(gb.x),b2f(gb.y),b2f(gb.z),b2f(gb.w) };
    float m1 = -3.0e38f, m2 = -3.0e38f;
    #pragma unroll
    for (int r = 0; r < 8; ++r) {
      float a = hv[r] + gv[r];
      m1 = fmaxf(m1, a); m2 = fmaxf(m2, hv[r]);
    }
    m1 = waveMax(m1); m2 = waveMax(m2);
    float s1 = 0.f, s2 = 0.f;
    #pragma unroll
    for (int r = 0; r < 8; ++r) {
      s1 += __expf(hv[r] + gv[r] - m1);
      s2 += __expf(hv[r] - m2);
    }
    s1 = waveSum(s1); s2 = waveSum(s2);
    if (lane == 0) {
      lsebuf[g]       = m1 + __logf(s1);
      lsebuf[NCF + g] = m2 + __logf(s2);
    }
  }
}

// ---------------- final: logZ - gold ----------------
extern "C" __global__ __launch_bounds__(512)
void crf_final(const float* __restrict__ lsebuf,
               const float* __restrict__ part,
               float* __restrict__ out){
  __shared__ float sredG[9];
  const int tidx = threadIdx.x;
  float acc = 0.f;
  for (int c = tidx; c < NCF; c += 512)
    if (c >= 1) acc += lsebuf[c] - lsebuf[NCF + c];
  if (tidx < NB) acc -= part[tidx];
  float s = blockSum8(acc, sredG);
  if (tidx == 0) out[0] = lsebuf[2*NCF] + s;
}

extern "C" void kernel_launch(void* const* d_in, const int* in_sizes, int n_in,
                              void* d_out, int out_size, void* d_ws, size_t ws_size,
                              hipStream_t stream){
  const float* logit = (const float*)d_in[0];
  const int* labels  = (const int*)d_in[1];
  const float* T     = (const float*)d_in[2];
  float* out = (float*)d_out;
  char* ws = (char*)d_ws;
  unsigned char* EAf = (unsigned char*)(ws + OFF_EAF);
  unsigned char* EAb = (unsigned char*)(ws + OFF_EAB);
  unsigned short* G  = (unsigned short*)(ws + OFF_G);
  unsigned short* H  = (unsigned short*)(ws + OFF_H);
  float* lsebuf = (float*)(ws + OFF_LSE);
  float* part   = (float*)(ws + OFF_GOLD);

  static bool attr_set = false;
  if (!attr_set) {
    (void)hipFuncSetAttribute((const void*)crf_chunks,
                        hipFuncAttributeMaxDynamicSharedMemorySize, SMEM_TOTAL);
    attr_set = true;
  }

  crf_prep  <<<NB, TPB, 0, stream>>>(logit, labels, T, EAf, EAb, part);
  crf_chunks<<<NB, TPB, SMEM_TOTAL, stream>>>(logit, EAf, EAb, G, H);
  crf_lse   <<<NCF/8, 512, 0, stream>>>(G, H, lsebuf);
  crf_final <<<1, 512, 0, stream>>>(lsebuf, part, out);
}